// Round 15
// baseline (650.089 us; speedup 1.0000x reference)
//
#include <hip/hip_runtime.h>
#include <cstdint>
#include <cstddef>

// GAT 2-layer (N=8192, D=256), flash softmax with rank-1 scores, bf16 MFMA PV.
// Identities:
//   m_i = leaky(s_i + max_{adj} d_j)        (leaky monotone)
//   exp(leaky(x)) = max(e^x, e^{a x})
//   p_ij = adj ? max(Ep_i*F_j, Gp_i*H_j) : 0,  F=e^d, H=e^{a d} (FH interleaved),
//   Ep = rl*e^{s-m}, Gp = rl*e^{a s-m}.
// R15: layer-1 combine8 deleted -- layer-2 gemm reads A = relu(sum of 8 pout
// partials) inline (same pairwise tree -> bit-identical A). R14's heterogeneous
// co-residency (mega1 = gemm+packbits, mega2 = rowstats+transp) kept. pv v8
// (barrier-free 64x64 wave tile, K-split x8) unchanged.
// ws: bits @8MB (8) | bitsT @16 (8) | small @24 | Bpack @25 (4) | pout @32 (64)

#define ALPHA 0.2f
#define NN 8192
#define DD 256

typedef __attribute__((ext_vector_type(8))) short short8;
typedef __attribute__((ext_vector_type(4))) float f32x4;

__device__ __forceinline__ unsigned bf16rne(float x) {
    union { float f; unsigned u; } c; c.f = x;
    return (c.u + 0x7fffu + ((c.u >> 16) & 1u)) >> 16;
}

#if __has_builtin(__builtin_amdgcn_cvt_pk_bf16_f32)
__device__ __forceinline__ unsigned pk_bf16(float a, float b) {
    return __builtin_bit_cast(unsigned, __builtin_amdgcn_cvt_pk_bf16_f32(a, b));
}
#else
__device__ __forceinline__ unsigned pk_bf16(float a, float b) {
    return bf16rne(a) | (bf16rne(b) << 16);
}
#endif

// ================= device phase bodies =================

// one adjacency row -> 128 u64 mask words; x2 unrolled (8 loads in flight)
__device__ __forceinline__ void packbits_dev(const int* __restrict__ adj,
                                             uint64_t* __restrict__ bits,
                                             int row, int lane) {
    const int* rowp = adj + (size_t)row * NN;
    uint64_t* dst = bits + (size_t)row * 128;
    for (int it = 0; it < 16; it++) {
        const int* p = rowp + it * 512;
        int a0 = p[lane];
        int a1 = p[64 + lane];
        int a2 = p[128 + lane];
        int a3 = p[192 + lane];
        int a4 = p[256 + lane];
        int a5 = p[320 + lane];
        int a6 = p[384 + lane];
        int a7 = p[448 + lane];
        uint64_t m0 = __ballot(a0 != 0);
        uint64_t m1 = __ballot(a1 != 0);
        uint64_t m2 = __ballot(a2 != 0);
        uint64_t m3 = __ballot(a3 != 0);
        uint64_t m4 = __ballot(a4 != 0);
        uint64_t m5 = __ballot(a5 != 0);
        uint64_t m6 = __ballot(a6 != 0);
        uint64_t m7 = __ballot(a7 != 0);
        if (lane == 0) {
            dst[it * 8 + 0] = m0; dst[it * 8 + 1] = m1;
            dst[it * 8 + 2] = m2; dst[it * 8 + 3] = m3;
            dst[it * 8 + 4] = m4; dst[it * 8 + 5] = m5;
            dst[it * 8 + 6] = m6; dst[it * 8 + 7] = m7;
        }
    }
}

// bits [i][w] -> bitsT [w][i], job in [0,512): 64x64 dword tile
__device__ __forceinline__ void transp_dev(const uint32_t* __restrict__ bits32,
                                           uint32_t* __restrict__ bitsT,
                                           int job, unsigned char* smem, int t) {
    uint32_t (*tile)[65] = (uint32_t (*)[65])smem;   // 16640 B
    const int i0 = (job >> 2) * 64;
    const int w0 = (job & 3) * 64;
#pragma unroll
    for (int p = 0; p < 4; p++) {
        int r = (t >> 4) + 16 * p;
        int c4 = (t & 15) * 4;
        uint4 v = *(const uint4*)(bits32 + (size_t)(i0 + r) * 256 + w0 + c4);
        tile[r][c4 + 0] = v.x; tile[r][c4 + 1] = v.y;
        tile[r][c4 + 2] = v.z; tile[r][c4 + 3] = v.w;
    }
    __syncthreads();
#pragma unroll
    for (int p = 0; p < 4; p++) {
        int wr = (t >> 4) + 16 * p;
        int i4 = (t & 15) * 4;
        uint4 o = {tile[i4][wr], tile[i4 + 1][wr], tile[i4 + 2][wr], tile[i4 + 3][wr]};
        *(uint4*)(bitsT + (size_t)(w0 + wr) * NN + i0 + i4) = o;
    }
}

// gemm+rowdots fused: Bpack tile + partial s/dd dots; job in [0,1024).
// If `partials` non-null, A is computed inline as relu(pairwise-sum of 8
// partials) -- bit-identical to the old combine8 output.
__device__ __forceinline__ void gemm_dev(const float* __restrict__ A,
                                         const float* __restrict__ partials,
                                         const float* __restrict__ B,
                                         unsigned short* __restrict__ Bpack,
                                         const float* __restrict__ a_src,
                                         const float* __restrict__ a_dst,
                                         float* __restrict__ s,
                                         float* __restrict__ dd,
                                         int job, unsigned char* smem, int t) {
    float (*At)[36] = (float (*)[36])smem;                 // 4608 B
    float2 (*Bs)[32] = (float2 (*)[32])(smem + 4608);      // 8192 B
    const int m0 = (job >> 2) * 32;
    const int cq = job & 3;
    const int r0 = (t >> 5) * 4;
    const int cl = t & 31;
    float acc[4][2];
#pragma unroll
    for (int i = 0; i < 4; i++) { acc[i][0] = 0.f; acc[i][1] = 0.f; }

    for (int k0 = 0; k0 < DD; k0 += 32) {
        {
            int row = t >> 3, kq = t & 7;
            size_t g4 = ((size_t)(m0 + row) * DD + k0 + kq * 4) >> 2;   // float4 idx
            float4 v;
            if (partials == nullptr) {
                v = ((const float4*)A)[g4];
            } else {
                const size_t S = (size_t)NN * DD / 4;
                const float4* pp = (const float4*)partials;
                float4 a0 = pp[g4],         a1 = pp[g4 + S];
                float4 a2 = pp[g4 + 2 * S], a3 = pp[g4 + 3 * S];
                float4 a4 = pp[g4 + 4 * S], a5 = pp[g4 + 5 * S];
                float4 a6 = pp[g4 + 6 * S], a7 = pp[g4 + 7 * S];
                v.x = fmaxf(((a0.x + a1.x) + (a2.x + a3.x)) + ((a4.x + a5.x) + (a6.x + a7.x)), 0.f);
                v.y = fmaxf(((a0.y + a1.y) + (a2.y + a3.y)) + ((a4.y + a5.y) + (a6.y + a7.y)), 0.f);
                v.z = fmaxf(((a0.z + a1.z) + (a2.z + a3.z)) + ((a4.z + a5.z) + (a6.z + a7.z)), 0.f);
                v.w = fmaxf(((a0.w + a1.w) + (a2.w + a3.w)) + ((a4.w + a5.w) + (a6.w + a7.w)), 0.f);
            }
            At[kq * 4 + 0][row] = v.x; At[kq * 4 + 1][row] = v.y;
            At[kq * 4 + 2][row] = v.z; At[kq * 4 + 3][row] = v.w;
        }
#pragma unroll
        for (int l2 = 0; l2 < 2; l2++) {
            int fi = l2 * 256 + t;
            int br = fi >> 4, bc4 = fi & 15;      // 32 k-rows x 16 float4 (64 cols)
            float4 v = *(const float4*)(B + (size_t)(k0 + br) * DD + cq * 64 + bc4 * 4);
            Bs[br][bc4 * 2] = {v.x, v.y};
            Bs[br][bc4 * 2 + 1] = {v.z, v.w};
        }
        __syncthreads();
#pragma unroll
        for (int k = 0; k < 32; k++) {
            float4 a0 = *(const float4*)&At[k][r0];
            float2 b = Bs[k][cl];
            float av[4] = {a0.x, a0.y, a0.z, a0.w};
#pragma unroll
            for (int i = 0; i < 4; i++) {
                acc[i][0] += av[i] * b.x;
                acc[i][1] += av[i] * b.y;
            }
        }
        __syncthreads();
    }

    // Bpack epilogue
    const int jt = m0 >> 5;
    const int lq = ((r0 >> 3) & 3) * 16;
    const int i8 = r0 & 4;
#pragma unroll
    for (int cc = 0; cc < 2; cc++) {
        int c = cq * 64 + cl * 2 + cc;
        int ct = c >> 4;
        int lane = lq + (c & 15);
        uint2 pk;
        pk.x = pk_bf16(acc[0][cc], acc[1][cc]);
        pk.y = pk_bf16(acc[2][cc], acc[3][cc]);
        *(uint2*)(Bpack + ((size_t)(jt * 16 + ct) * 64 + lane) * 8 + i8) = pk;
    }

    // rowdots epilogue: partial dots over this block's 64 cols
    const int c0 = cq * 64 + cl * 2;
    float as0 = a_src[c0], as1 = a_src[c0 + 1];
    float ad0 = a_dst[c0], ad1 = a_dst[c0 + 1];
    float ps[4], pd[4];
#pragma unroll
    for (int i = 0; i < 4; i++) {
        ps[i] = acc[i][0] * as0 + acc[i][1] * as1;
        pd[i] = acc[i][0] * ad0 + acc[i][1] * ad1;
    }
#pragma unroll
    for (int off = 16; off; off >>= 1) {
#pragma unroll
        for (int i = 0; i < 4; i++) {
            ps[i] += __shfl_xor(ps[i], off);
            pd[i] += __shfl_xor(pd[i], off);
        }
    }
    if (cl == 0) {
#pragma unroll
        for (int i = 0; i < 4; i++) {
            atomicAdd(&s[m0 + r0 + i], ps[i]);
            atomicAdd(&dd[m0 + r0 + i], pd[i]);
        }
    }
}

// rowstats: 4 rows (i0 = job*4), lane-contiguous loads, masks via LDS
__device__ __forceinline__ void rowstats_dev(const uint32_t* __restrict__ bits32,
                                             const float* __restrict__ s,
                                             const float* __restrict__ dd,
                                             const float* __restrict__ FH,
                                             float* __restrict__ Ep,
                                             float* __restrict__ Gp,
                                             int job, unsigned char* smem, int t) {
    uint32_t* smk = (uint32_t*)smem;                       // 4096 B
    float (*red)[4] = (float (*)[4])(smem + 4096);         // 64 B
    float* sEm = (float*)(smem + 4096 + 64);
    float* sEa = (float*)(smem + 4096 + 80);
    const int i0 = job * 4;
    const int wave = t >> 6, lane = t & 63;
    {
        const uint4* src = (const uint4*)(bits32 + (size_t)i0 * 256);
        ((uint4*)smk)[t] = src[t];
    }
    __syncthreads();

    float mx[4];
#pragma unroll
    for (int r = 0; r < 4; r++) mx[r] = -3.0e38f;
#pragma unroll
    for (int q = 0; q < 8; q++) {
        float4 v = *(const float4*)(dd + 4 * (t + 256 * q));
        const int wq = 32 * q + (t >> 3);
        const int sh = (t & 7) * 4;
#pragma unroll
        for (int r = 0; r < 4; r++) {
            uint32_t b = smk[r * 256 + wq] >> sh;
            mx[r] = fmaxf(mx[r], (b & 1u) ? v.x : -3.0e38f);
            mx[r] = fmaxf(mx[r], (b & 2u) ? v.y : -3.0e38f);
            mx[r] = fmaxf(mx[r], (b & 4u) ? v.z : -3.0e38f);
            mx[r] = fmaxf(mx[r], (b & 8u) ? v.w : -3.0e38f);
        }
    }
#pragma unroll
    for (int r = 0; r < 4; r++) {
#pragma unroll
        for (int off = 32; off; off >>= 1) mx[r] = fmaxf(mx[r], __shfl_down(mx[r], off));
    }
    if (lane == 0) {
#pragma unroll
        for (int r = 0; r < 4; r++) red[wave][r] = mx[r];
    }
    __syncthreads();
    if (t < 4) {
        float dmax = fmaxf(fmaxf(red[0][t], red[1][t]), fmaxf(red[2][t], red[3][t]));
        float si = s[i0 + t];
        float e = si + dmax;
        float m = e >= 0.f ? e : ALPHA * e;
        sEm[t] = __expf(si - m);
        sEa[t] = __expf(ALPHA * si - m);
    }
    __syncthreads();
    float em[4], ea[4], sm[4];
#pragma unroll
    for (int r = 0; r < 4; r++) { em[r] = sEm[r]; ea[r] = sEa[r]; sm[r] = 0.f; }

#pragma unroll
    for (int q = 0; q < 16; q++) {
        float4 v = *(const float4*)(FH + 4 * (t + 256 * q));
        const int wq = 16 * q + (t >> 4);
        const int sh = (t & 15) * 2;
#pragma unroll
        for (int r = 0; r < 4; r++) {
            uint32_t b = smk[r * 256 + wq] >> sh;
            float c0 = fmaxf(em[r] * v.x, ea[r] * v.y);
            float c1 = fmaxf(em[r] * v.z, ea[r] * v.w);
            sm[r] += (b & 1u) ? c0 : 0.f;
            sm[r] += (b & 2u) ? c1 : 0.f;
        }
    }
#pragma unroll
    for (int r = 0; r < 4; r++) {
#pragma unroll
        for (int off = 32; off; off >>= 1) sm[r] += __shfl_down(sm[r], off);
    }
    __syncthreads();
    if (lane == 0) {
#pragma unroll
        for (int r = 0; r < 4; r++) red[wave][r] = sm[r];
    }
    __syncthreads();
    if (t < 4) {
        float rl = 1.0f / (red[0][t] + red[1][t] + red[2][t] + red[3][t]);
        Ep[i0 + t] = rl * sEm[t];
        Gp[i0 + t] = rl * sEa[t];
    }
}

// ================= kernels =================

// mega1: gemm(layer1) + packbits interleaved, 3072 blocks.
__global__ __launch_bounds__(256) void mega1(const float* __restrict__ A,
                                             const float* __restrict__ W,
                                             unsigned short* __restrict__ Bpack,
                                             const float* __restrict__ a_src,
                                             const float* __restrict__ a_dst,
                                             float* __restrict__ s,
                                             float* __restrict__ dd,
                                             const int* __restrict__ adj,
                                             uint64_t* __restrict__ bits) {
    __shared__ __align__(16) unsigned char smem[12800];
    const int bx = blockIdx.x;
    const int t = threadIdx.x;
    const int sel = bx % 3;
    const int base = bx / 3;
    if (sel == 0) {
        gemm_dev(A, nullptr, W, Bpack, a_src, a_dst, s, dd, base, smem, t);
    } else {
        const int row = base * 8 + (sel - 1) * 4 + (t >> 6);
        packbits_dev(adj, bits, row, t & 63);
    }
}

// mega2: rowstats + transp interleaved, 2560 blocks.
__global__ __launch_bounds__(256) void mega2(const uint32_t* __restrict__ bits32,
                                             uint32_t* __restrict__ bitsT,
                                             const float* __restrict__ s,
                                             const float* __restrict__ dd,
                                             const float* __restrict__ FH,
                                             float* __restrict__ Ep,
                                             float* __restrict__ Gp) {
    __shared__ __align__(16) unsigned char smem[16640];
    const int bx = blockIdx.x;
    const int t = threadIdx.x;
    const int sel = bx % 5;
    const int base = bx / 5;
    if (sel == 0) {
        transp_dev(bits32, bitsT, base, smem, t);
    } else {
        rowstats_dev(bits32, s, dd, FH, Ep, Gp, base * 4 + (sel - 1), smem, t);
    }
}

// layer-2 gemm: A = relu(sum of 8 pout partials), computed inline
__global__ __launch_bounds__(256) void k_gemm_fused(const float* partials, const float* W,
                                                    unsigned short* Bpack,
                                                    const float* a_src, const float* a_dst,
                                                    float* s, float* dd) {
    __shared__ __align__(16) unsigned char smem[12800];
    gemm_dev(nullptr, partials, W, Bpack, a_src, a_dst, s, dd, blockIdx.x, smem, threadIdx.x);
}
__global__ __launch_bounds__(256) void k_rowstats(const uint32_t* bits32, const float* s,
                                                  const float* dd, const float* FH,
                                                  float* Ep, float* Gp) {
    __shared__ __align__(16) unsigned char smem[4200];
    rowstats_dev(bits32, s, dd, FH, Ep, Gp, blockIdx.x, smem, threadIdx.x);
}

// ------- fhgen: FH[2i]=exp(dd), FH[2i+1]=exp(a*dd) -------
__global__ __launch_bounds__(256) void fhgen(const float* __restrict__ dd,
                                             float* __restrict__ FH) {
    int i = blockIdx.x * 256 + threadIdx.x;
    float d = dd[i];
    FH[2 * i] = __expf(d);
    FH[2 * i + 1] = __expf(ALPHA * d);
}

// ---------------- pv v8: barrier-free, wave = 64 rows x 64 cols, pout[ks] = P @ Wh ----------------
__global__ __launch_bounds__(256, 4) void pv_mfma(const unsigned short* __restrict__ Bpack,
                                                  const uint32_t* __restrict__ bitsT,
                                                  const float* __restrict__ FH,
                                                  const float* __restrict__ Ep,
                                                  const float* __restrict__ Gp,
                                                  float* __restrict__ pout) {
    const int t = threadIdx.x;
    const int w = t >> 6, l = t & 63;
    const int bx = blockIdx.x;
    const int ks = bx & 7;
    const int cg = (bx >> 3) & 3;
    const int i0 = (bx >> 5) * 256 + w * 64;     // wave's 64-row base
    const int kbase = ks * 32;                   // 32 chunks per eighth

    const int rl16 = l & 15;
    const int ko = (l >> 4) * 8;                 // k-octet within 32-wide chunk
    const int r0 = i0 + rl16;
    float Epv[4], Gpv[4];
#pragma unroll
    for (int f = 0; f < 4; f++) {
        Epv[f] = Ep[r0 + 16 * f];
        Gpv[f] = Gp[r0 + 16 * f];
    }

    const unsigned short* bb = Bpack + ((size_t)(cg * 4) * 64 + l) * 8;
    const uint32_t* btb = bitsT + i0 + rl16;     // + cc*NN + 16*f

    f32x4 acc[4][4];
#pragma unroll
    for (int i = 0; i < 4; i++)
#pragma unroll
        for (int q = 0; q < 4; q++) acc[i][q] = (f32x4){0.f, 0.f, 0.f, 0.f};

    for (int jl = 0; jl < 32; jl++) {
        const int cc = kbase + jl;
        const unsigned short* bp = bb + (size_t)cc * 8192;
        short8 B0 = *(const short8*)(bp);
        short8 B1 = *(const short8*)(bp + 512);
        short8 B2 = *(const short8*)(bp + 1024);
        short8 B3 = *(const short8*)(bp + 1536);
        const uint32_t* btc = btb + (size_t)cc * NN;
        uint32_t bw0 = btc[0];
        uint32_t bw1 = btc[16];
        uint32_t bw2 = btc[32];
        uint32_t bw3 = btc[48];
        const float* fp = FH + 2 * (size_t)(cc * 32 + ko);
        float4 f0 = *(const float4*)(fp);
        float4 f1 = *(const float4*)(fp + 4);
        float4 f2 = *(const float4*)(fp + 8);
        float4 f3 = *(const float4*)(fp + 12);

        uint32_t bwa[4] = {bw0, bw1, bw2, bw3};
#pragma unroll
        for (int f = 0; f < 4; f++) {
            uint32_t wl = bwa[f] >> ko;
            float Epf = Epv[f], Gpf = Gpv[f];
            float p0 = (wl & 1u)   ? fmaxf(Epf * f0.x, Gpf * f0.y) : 0.f;
            float p1 = (wl & 2u)   ? fmaxf(Epf * f0.z, Gpf * f0.w) : 0.f;
            float p2 = (wl & 4u)   ? fmaxf(Epf * f1.x, Gpf * f1.y) : 0.f;
            float p3 = (wl & 8u)   ? fmaxf(Epf * f1.z, Gpf * f1.w) : 0.f;
            float p4 = (wl & 16u)  ? fmaxf(Epf * f2.x, Gpf * f2.y) : 0.f;
            float p5 = (wl & 32u)  ? fmaxf(Epf * f2.z, Gpf * f2.w) : 0.f;
            float p6 = (wl & 64u)  ? fmaxf(Epf * f3.x, Gpf * f3.y) : 0.f;
            float p7 = (wl & 128u) ? fmaxf(Epf * f3.z, Gpf * f3.w) : 0.f;
            uint4 au = {pk_bf16(p0, p1), pk_bf16(p2, p3), pk_bf16(p4, p5), pk_bf16(p6, p7)};
            short8 af = __builtin_bit_cast(short8, au);
            acc[f][0] = __builtin_amdgcn_mfma_f32_16x16x32_bf16(af, B0, acc[f][0], 0, 0, 0);
            acc[f][1] = __builtin_amdgcn_mfma_f32_16x16x32_bf16(af, B1, acc[f][1], 0, 0, 0);
            acc[f][2] = __builtin_amdgcn_mfma_f32_16x16x32_bf16(af, B2, acc[f][2], 0, 0, 0);
            acc[f][3] = __builtin_amdgcn_mfma_f32_16x16x32_bf16(af, B3, acc[f][3], 0, 0, 0);
        }
    }

    float* outp = pout + (size_t)ks * NN * DD;
    // C layout: col = l&15, row = (l>>4)*4 + r
#pragma unroll
    for (int f = 0; f < 4; f++) {
        const int orow = i0 + 16 * f + (l >> 4) * 4;
#pragma unroll
        for (int q = 0; q < 4; q++) {
            const int ocol = cg * 64 + q * 16 + rl16;
#pragma unroll
            for (int r = 0; r < 4; r++)
                outp[(size_t)(orow + r) * DD + ocol] = acc[f][q][r];
        }
    }
}

// -------- out = relu(sum of 8 partials) --------
__global__ __launch_bounds__(256) void combine8(const float* __restrict__ p,
                                                float* __restrict__ out) {
    const size_t S = (size_t)NN * DD / 4;   // float4 stride between partials
    size_t idx = (size_t)blockIdx.x * 256 + threadIdx.x;
    float4 a0 = ((const float4*)p)[idx];
    float4 a1 = ((const float4*)p)[idx + S];
    float4 a2 = ((const float4*)p)[idx + 2 * S];
    float4 a3 = ((const float4*)p)[idx + 3 * S];
    float4 a4 = ((const float4*)p)[idx + 4 * S];
    float4 a5 = ((const float4*)p)[idx + 5 * S];
    float4 a6 = ((const float4*)p)[idx + 6 * S];
    float4 a7 = ((const float4*)p)[idx + 7 * S];
    float4 o;
    o.x = fmaxf(((a0.x + a1.x) + (a2.x + a3.x)) + ((a4.x + a5.x) + (a6.x + a7.x)), 0.f);
    o.y = fmaxf(((a0.y + a1.y) + (a2.y + a3.y)) + ((a4.y + a5.y) + (a6.y + a7.y)), 0.f);
    o.z = fmaxf(((a0.z + a1.z) + (a2.z + a3.z)) + ((a4.z + a5.z) + (a6.z + a7.z)), 0.f);
    o.w = fmaxf(((a0.w + a1.w) + (a2.w + a3.w)) + ((a4.w + a5.w) + (a6.w + a7.w)), 0.f);
    ((float4*)out)[idx] = o;
}

extern "C" void kernel_launch(void* const* d_in, const int* in_sizes, int n_in,
                              void* d_out, int out_size, void* d_ws, size_t ws_size,
                              hipStream_t stream) {
    const float* x   = (const float*)d_in[0];
    const int* adj   = (const int*)d_in[1];
    const float* W1  = (const float*)d_in[2];
    const float* a1s = (const float*)d_in[3];
    const float* a1d = (const float*)d_in[4];
    const float* W2  = (const float*)d_in[5];
    const float* a2s = (const float*)d_in[6];
    const float* a2d = (const float*)d_in[7];
    float* out = (float*)d_out;

    char* ws = (char*)d_ws;
    const size_t MB = 1024ull * 1024ull;
    uint64_t*       bits  = (uint64_t*)(ws + 8 * MB);        // 8 MB
    uint32_t*       bits32= (uint32_t*)bits;
    uint32_t*       bitsT = (uint32_t*)(ws + 16 * MB);       // 8 MB
    float*          sArr  = (float*)(ws + 24 * MB);
    float*          ddA   = sArr + NN;
    float*          EpA   = sArr + 2 * NN;
    float*          GpA   = sArr + 3 * NN;
    float*          FHA   = sArr + 4 * NN;                   // 2*NN floats
    unsigned short* Bpack = (unsigned short*)(ws + 25 * MB); // 4 MB
    float*          pout  = (float*)(ws + 32 * MB);          // 64 MB (8 partials)

    // ---------------- Layer 1 (+ shared preprocessing overlapped) ----------------
    hipMemsetAsync(sArr, 0, 2 * NN * sizeof(float), stream);   // zero s, dd
    mega1<<<dim3(3072), dim3(256), 0, stream>>>(x, W1, Bpack, a1s, a1d, sArr, ddA,
                                                adj, bits);
    fhgen<<<dim3(32), dim3(256), 0, stream>>>(ddA, FHA);
    mega2<<<dim3(2560), dim3(256), 0, stream>>>(bits32, bitsT, sArr, ddA, FHA, EpA, GpA);
    pv_mfma<<<dim3(1024), dim3(256), 0, stream>>>(Bpack, bitsT, FHA, EpA, GpA, pout);

    // ---------------- Layer 2 (combine8 of layer 1 fused into gemm A-load) ----------------
    hipMemsetAsync(sArr, 0, 2 * NN * sizeof(float), stream);   // zero s, dd
    k_gemm_fused<<<dim3(1024), dim3(256), 0, stream>>>(pout, W2, Bpack, a2s, a2d, sArr, ddA);
    fhgen<<<dim3(32), dim3(256), 0, stream>>>(ddA, FHA);
    k_rowstats<<<dim3(2048), dim3(256), 0, stream>>>(bits32, sArr, ddA, FHA, EpA, GpA);
    pv_mfma<<<dim3(1024), dim3(256), 0, stream>>>(Bpack, bitsT, FHA, EpA, GpA, pout);
    combine8<<<dim3(2048), dim3(256), 0, stream>>>(pout, out);
}

// Round 16
// 642.628 us; speedup vs baseline: 1.0116x; 1.0116x over previous
//
#include <hip/hip_runtime.h>
#include <cstdint>
#include <cstddef>

// GAT 2-layer (N=8192, D=256), flash softmax with rank-1 scores, bf16 MFMA PV.
// Identities:
//   m_i = leaky(s_i + max_{adj} d_j)        (leaky monotone)
//   exp(leaky(x)) = max(e^x, e^{a x})
//   p_ij = adj ? max(Ep_i*F_j, Gp_i*H_j) : 0,  F=e^d, H=e^{a d} (FH interleaved),
//   Ep = rl*e^{s-m}, Gp = rl*e^{a s-m}.
// R16: R14 structure (combine8 restored -- R15's gemm-side combine re-read 256 MB
// and was a wash) + s/dd memsets deleted: gemm writes per-col-quarter partials
// s4/dd4 (unique writer, no atomics), fhgen sums them. 12 dispatches total.
// ws: bits @8MB (8) | bitsT @16 (8) | small @24 | Bpack @25 (4) | pout @32 (64)

#define ALPHA 0.2f
#define NN 8192
#define DD 256

typedef __attribute__((ext_vector_type(8))) short short8;
typedef __attribute__((ext_vector_type(4))) float f32x4;

__device__ __forceinline__ unsigned bf16rne(float x) {
    union { float f; unsigned u; } c; c.f = x;
    return (c.u + 0x7fffu + ((c.u >> 16) & 1u)) >> 16;
}

#if __has_builtin(__builtin_amdgcn_cvt_pk_bf16_f32)
__device__ __forceinline__ unsigned pk_bf16(float a, float b) {
    return __builtin_bit_cast(unsigned, __builtin_amdgcn_cvt_pk_bf16_f32(a, b));
}
#else
__device__ __forceinline__ unsigned pk_bf16(float a, float b) {
    return bf16rne(a) | (bf16rne(b) << 16);
}
#endif

// ================= device phase bodies =================

// one adjacency row -> 128 u64 mask words; x2 unrolled (8 loads in flight)
__device__ __forceinline__ void packbits_dev(const int* __restrict__ adj,
                                             uint64_t* __restrict__ bits,
                                             int row, int lane) {
    const int* rowp = adj + (size_t)row * NN;
    uint64_t* dst = bits + (size_t)row * 128;
    for (int it = 0; it < 16; it++) {
        const int* p = rowp + it * 512;
        int a0 = p[lane];
        int a1 = p[64 + lane];
        int a2 = p[128 + lane];
        int a3 = p[192 + lane];
        int a4 = p[256 + lane];
        int a5 = p[320 + lane];
        int a6 = p[384 + lane];
        int a7 = p[448 + lane];
        uint64_t m0 = __ballot(a0 != 0);
        uint64_t m1 = __ballot(a1 != 0);
        uint64_t m2 = __ballot(a2 != 0);
        uint64_t m3 = __ballot(a3 != 0);
        uint64_t m4 = __ballot(a4 != 0);
        uint64_t m5 = __ballot(a5 != 0);
        uint64_t m6 = __ballot(a6 != 0);
        uint64_t m7 = __ballot(a7 != 0);
        if (lane == 0) {
            dst[it * 8 + 0] = m0; dst[it * 8 + 1] = m1;
            dst[it * 8 + 2] = m2; dst[it * 8 + 3] = m3;
            dst[it * 8 + 4] = m4; dst[it * 8 + 5] = m5;
            dst[it * 8 + 6] = m6; dst[it * 8 + 7] = m7;
        }
    }
}

// bits [i][w] -> bitsT [w][i], job in [0,512): 64x64 dword tile
__device__ __forceinline__ void transp_dev(const uint32_t* __restrict__ bits32,
                                           uint32_t* __restrict__ bitsT,
                                           int job, unsigned char* smem, int t) {
    uint32_t (*tile)[65] = (uint32_t (*)[65])smem;   // 16640 B
    const int i0 = (job >> 2) * 64;
    const int w0 = (job & 3) * 64;
#pragma unroll
    for (int p = 0; p < 4; p++) {
        int r = (t >> 4) + 16 * p;
        int c4 = (t & 15) * 4;
        uint4 v = *(const uint4*)(bits32 + (size_t)(i0 + r) * 256 + w0 + c4);
        tile[r][c4 + 0] = v.x; tile[r][c4 + 1] = v.y;
        tile[r][c4 + 2] = v.z; tile[r][c4 + 3] = v.w;
    }
    __syncthreads();
#pragma unroll
    for (int p = 0; p < 4; p++) {
        int wr = (t >> 4) + 16 * p;
        int i4 = (t & 15) * 4;
        uint4 o = {tile[i4][wr], tile[i4 + 1][wr], tile[i4 + 2][wr], tile[i4 + 3][wr]};
        *(uint4*)(bitsT + (size_t)(w0 + wr) * NN + i0 + i4) = o;
    }
}

// gemm+rowdots fused: Bpack tile + per-quarter partial s/dd dots; job in [0,1024).
// s4/dd4 layout: [cq][row] -- unique writer per (cq,row), no atomics, no zero-init.
__device__ __forceinline__ void gemm_dev(const float* __restrict__ A,
                                         const float* __restrict__ B,
                                         unsigned short* __restrict__ Bpack,
                                         const float* __restrict__ a_src,
                                         const float* __restrict__ a_dst,
                                         float* __restrict__ s4,
                                         float* __restrict__ dd4,
                                         int job, unsigned char* smem, int t) {
    float (*At)[36] = (float (*)[36])smem;                 // 4608 B
    float2 (*Bs)[32] = (float2 (*)[32])(smem + 4608);      // 8192 B
    const int m0 = (job >> 2) * 32;
    const int cq = job & 3;
    const int r0 = (t >> 5) * 4;
    const int cl = t & 31;
    float acc[4][2];
#pragma unroll
    for (int i = 0; i < 4; i++) { acc[i][0] = 0.f; acc[i][1] = 0.f; }

    for (int k0 = 0; k0 < DD; k0 += 32) {
        {
            int row = t >> 3, kq = t & 7;
            float4 v = *(const float4*)(A + (size_t)(m0 + row) * DD + k0 + kq * 4);
            At[kq * 4 + 0][row] = v.x; At[kq * 4 + 1][row] = v.y;
            At[kq * 4 + 2][row] = v.z; At[kq * 4 + 3][row] = v.w;
        }
#pragma unroll
        for (int l2 = 0; l2 < 2; l2++) {
            int fi = l2 * 256 + t;
            int br = fi >> 4, bc4 = fi & 15;      // 32 k-rows x 16 float4 (64 cols)
            float4 v = *(const float4*)(B + (size_t)(k0 + br) * DD + cq * 64 + bc4 * 4);
            Bs[br][bc4 * 2] = {v.x, v.y};
            Bs[br][bc4 * 2 + 1] = {v.z, v.w};
        }
        __syncthreads();
#pragma unroll
        for (int k = 0; k < 32; k++) {
            float4 a0 = *(const float4*)&At[k][r0];
            float2 b = Bs[k][cl];
            float av[4] = {a0.x, a0.y, a0.z, a0.w};
#pragma unroll
            for (int i = 0; i < 4; i++) {
                acc[i][0] += av[i] * b.x;
                acc[i][1] += av[i] * b.y;
            }
        }
        __syncthreads();
    }

    // Bpack epilogue
    const int jt = m0 >> 5;
    const int lq = ((r0 >> 3) & 3) * 16;
    const int i8 = r0 & 4;
#pragma unroll
    for (int cc = 0; cc < 2; cc++) {
        int c = cq * 64 + cl * 2 + cc;
        int ct = c >> 4;
        int lane = lq + (c & 15);
        uint2 pk;
        pk.x = pk_bf16(acc[0][cc], acc[1][cc]);
        pk.y = pk_bf16(acc[2][cc], acc[3][cc]);
        *(uint2*)(Bpack + ((size_t)(jt * 16 + ct) * 64 + lane) * 8 + i8) = pk;
    }

    // rowdots epilogue: partial dots over this block's 64 cols -> s4/dd4[cq][row]
    const int c0 = cq * 64 + cl * 2;
    float as0 = a_src[c0], as1 = a_src[c0 + 1];
    float ad0 = a_dst[c0], ad1 = a_dst[c0 + 1];
    float ps[4], pd[4];
#pragma unroll
    for (int i = 0; i < 4; i++) {
        ps[i] = acc[i][0] * as0 + acc[i][1] * as1;
        pd[i] = acc[i][0] * ad0 + acc[i][1] * ad1;
    }
#pragma unroll
    for (int off = 16; off; off >>= 1) {
#pragma unroll
        for (int i = 0; i < 4; i++) {
            ps[i] += __shfl_xor(ps[i], off);
            pd[i] += __shfl_xor(pd[i], off);
        }
    }
    if (cl == 0) {
#pragma unroll
        for (int i = 0; i < 4; i++) {
            s4[(size_t)cq * NN + m0 + r0 + i] = ps[i];
            dd4[(size_t)cq * NN + m0 + r0 + i] = pd[i];
        }
    }
}

// rowstats: 4 rows (i0 = job*4), lane-contiguous loads, masks via LDS
__device__ __forceinline__ void rowstats_dev(const uint32_t* __restrict__ bits32,
                                             const float* __restrict__ s,
                                             const float* __restrict__ dd,
                                             const float* __restrict__ FH,
                                             float* __restrict__ Ep,
                                             float* __restrict__ Gp,
                                             int job, unsigned char* smem, int t) {
    uint32_t* smk = (uint32_t*)smem;                       // 4096 B
    float (*red)[4] = (float (*)[4])(smem + 4096);         // 64 B
    float* sEm = (float*)(smem + 4096 + 64);
    float* sEa = (float*)(smem + 4096 + 80);
    const int i0 = job * 4;
    const int wave = t >> 6, lane = t & 63;
    {
        const uint4* src = (const uint4*)(bits32 + (size_t)i0 * 256);
        ((uint4*)smk)[t] = src[t];
    }
    __syncthreads();

    float mx[4];
#pragma unroll
    for (int r = 0; r < 4; r++) mx[r] = -3.0e38f;
#pragma unroll
    for (int q = 0; q < 8; q++) {
        float4 v = *(const float4*)(dd + 4 * (t + 256 * q));
        const int wq = 32 * q + (t >> 3);
        const int sh = (t & 7) * 4;
#pragma unroll
        for (int r = 0; r < 4; r++) {
            uint32_t b = smk[r * 256 + wq] >> sh;
            mx[r] = fmaxf(mx[r], (b & 1u) ? v.x : -3.0e38f);
            mx[r] = fmaxf(mx[r], (b & 2u) ? v.y : -3.0e38f);
            mx[r] = fmaxf(mx[r], (b & 4u) ? v.z : -3.0e38f);
            mx[r] = fmaxf(mx[r], (b & 8u) ? v.w : -3.0e38f);
        }
    }
#pragma unroll
    for (int r = 0; r < 4; r++) {
#pragma unroll
        for (int off = 32; off; off >>= 1) mx[r] = fmaxf(mx[r], __shfl_down(mx[r], off));
    }
    if (lane == 0) {
#pragma unroll
        for (int r = 0; r < 4; r++) red[wave][r] = mx[r];
    }
    __syncthreads();
    if (t < 4) {
        float dmax = fmaxf(fmaxf(red[0][t], red[1][t]), fmaxf(red[2][t], red[3][t]));
        float si = s[i0 + t];
        float e = si + dmax;
        float m = e >= 0.f ? e : ALPHA * e;
        sEm[t] = __expf(si - m);
        sEa[t] = __expf(ALPHA * si - m);
    }
    __syncthreads();
    float em[4], ea[4], sm[4];
#pragma unroll
    for (int r = 0; r < 4; r++) { em[r] = sEm[r]; ea[r] = sEa[r]; sm[r] = 0.f; }

#pragma unroll
    for (int q = 0; q < 16; q++) {
        float4 v = *(const float4*)(FH + 4 * (t + 256 * q));
        const int wq = 16 * q + (t >> 4);
        const int sh = (t & 15) * 2;
#pragma unroll
        for (int r = 0; r < 4; r++) {
            uint32_t b = smk[r * 256 + wq] >> sh;
            float c0 = fmaxf(em[r] * v.x, ea[r] * v.y);
            float c1 = fmaxf(em[r] * v.z, ea[r] * v.w);
            sm[r] += (b & 1u) ? c0 : 0.f;
            sm[r] += (b & 2u) ? c1 : 0.f;
        }
    }
#pragma unroll
    for (int r = 0; r < 4; r++) {
#pragma unroll
        for (int off = 32; off; off >>= 1) sm[r] += __shfl_down(sm[r], off);
    }
    __syncthreads();
    if (lane == 0) {
#pragma unroll
        for (int r = 0; r < 4; r++) red[wave][r] = sm[r];
    }
    __syncthreads();
    if (t < 4) {
        float rl = 1.0f / (red[0][t] + red[1][t] + red[2][t] + red[3][t]);
        Ep[i0 + t] = rl * sEm[t];
        Gp[i0 + t] = rl * sEa[t];
    }
}

// ================= kernels =================

// mega1: gemm(layer1) + packbits interleaved, 3072 blocks.
__global__ __launch_bounds__(256) void mega1(const float* __restrict__ A,
                                             const float* __restrict__ W,
                                             unsigned short* __restrict__ Bpack,
                                             const float* __restrict__ a_src,
                                             const float* __restrict__ a_dst,
                                             float* __restrict__ s4,
                                             float* __restrict__ dd4,
                                             const int* __restrict__ adj,
                                             uint64_t* __restrict__ bits) {
    __shared__ __align__(16) unsigned char smem[12800];
    const int bx = blockIdx.x;
    const int t = threadIdx.x;
    const int sel = bx % 3;
    const int base = bx / 3;
    if (sel == 0) {
        gemm_dev(A, W, Bpack, a_src, a_dst, s4, dd4, base, smem, t);
    } else {
        const int row = base * 8 + (sel - 1) * 4 + (t >> 6);
        packbits_dev(adj, bits, row, t & 63);
    }
}

// mega2: rowstats + transp interleaved, 2560 blocks.
__global__ __launch_bounds__(256) void mega2(const uint32_t* __restrict__ bits32,
                                             uint32_t* __restrict__ bitsT,
                                             const float* __restrict__ s,
                                             const float* __restrict__ dd,
                                             const float* __restrict__ FH,
                                             float* __restrict__ Ep,
                                             float* __restrict__ Gp) {
    __shared__ __align__(16) unsigned char smem[16640];
    const int bx = blockIdx.x;
    const int t = threadIdx.x;
    const int sel = bx % 5;
    const int base = bx / 5;
    if (sel == 0) {
        transp_dev(bits32, bitsT, base, smem, t);
    } else {
        rowstats_dev(bits32, s, dd, FH, Ep, Gp, base * 4 + (sel - 1), smem, t);
    }
}

// standalone gemm (layer 2) and rowstats (layer 2)
__global__ __launch_bounds__(256) void k_gemm(const float* A, const float* W,
                                              unsigned short* Bpack,
                                              const float* a_src, const float* a_dst,
                                              float* s4, float* dd4) {
    __shared__ __align__(16) unsigned char smem[12800];
    gemm_dev(A, W, Bpack, a_src, a_dst, s4, dd4, blockIdx.x, smem, threadIdx.x);
}
__global__ __launch_bounds__(256) void k_rowstats(const uint32_t* bits32, const float* s,
                                                  const float* dd, const float* FH,
                                                  float* Ep, float* Gp) {
    __shared__ __align__(16) unsigned char smem[4200];
    rowstats_dev(bits32, s, dd, FH, Ep, Gp, blockIdx.x, smem, threadIdx.x);
}

// ------- fhgen: sum s4/dd4 partials -> s, dd; FH[2i]=exp(dd), FH[2i+1]=exp(a*dd) -------
__global__ __launch_bounds__(256) void fhgen(const float* __restrict__ s4,
                                             const float* __restrict__ dd4,
                                             float* __restrict__ s,
                                             float* __restrict__ dd,
                                             float* __restrict__ FH) {
    int i = blockIdx.x * 256 + threadIdx.x;
    float ssum = (s4[i] + s4[i + NN]) + (s4[i + 2 * NN] + s4[i + 3 * NN]);
    float dsum = (dd4[i] + dd4[i + NN]) + (dd4[i + 2 * NN] + dd4[i + 3 * NN]);
    s[i] = ssum;
    dd[i] = dsum;
    FH[2 * i] = __expf(dsum);
    FH[2 * i + 1] = __expf(ALPHA * dsum);
}

// ---------------- pv v8: barrier-free, wave = 64 rows x 64 cols, pout[ks] = P @ Wh ----------------
__global__ __launch_bounds__(256, 4) void pv_mfma(const unsigned short* __restrict__ Bpack,
                                                  const uint32_t* __restrict__ bitsT,
                                                  const float* __restrict__ FH,
                                                  const float* __restrict__ Ep,
                                                  const float* __restrict__ Gp,
                                                  float* __restrict__ pout) {
    const int t = threadIdx.x;
    const int w = t >> 6, l = t & 63;
    const int bx = blockIdx.x;
    const int ks = bx & 7;
    const int cg = (bx >> 3) & 3;
    const int i0 = (bx >> 5) * 256 + w * 64;     // wave's 64-row base
    const int kbase = ks * 32;                   // 32 chunks per eighth

    const int rl16 = l & 15;
    const int ko = (l >> 4) * 8;                 // k-octet within 32-wide chunk
    const int r0 = i0 + rl16;
    float Epv[4], Gpv[4];
#pragma unroll
    for (int f = 0; f < 4; f++) {
        Epv[f] = Ep[r0 + 16 * f];
        Gpv[f] = Gp[r0 + 16 * f];
    }

    const unsigned short* bb = Bpack + ((size_t)(cg * 4) * 64 + l) * 8;
    const uint32_t* btb = bitsT + i0 + rl16;     // + cc*NN + 16*f

    f32x4 acc[4][4];
#pragma unroll
    for (int i = 0; i < 4; i++)
#pragma unroll
        for (int q = 0; q < 4; q++) acc[i][q] = (f32x4){0.f, 0.f, 0.f, 0.f};

    for (int jl = 0; jl < 32; jl++) {
        const int cc = kbase + jl;
        const unsigned short* bp = bb + (size_t)cc * 8192;
        short8 B0 = *(const short8*)(bp);
        short8 B1 = *(const short8*)(bp + 512);
        short8 B2 = *(const short8*)(bp + 1024);
        short8 B3 = *(const short8*)(bp + 1536);
        const uint32_t* btc = btb + (size_t)cc * NN;
        uint32_t bw0 = btc[0];
        uint32_t bw1 = btc[16];
        uint32_t bw2 = btc[32];
        uint32_t bw3 = btc[48];
        const float* fp = FH + 2 * (size_t)(cc * 32 + ko);
        float4 f0 = *(const float4*)(fp);
        float4 f1 = *(const float4*)(fp + 4);
        float4 f2 = *(const float4*)(fp + 8);
        float4 f3 = *(const float4*)(fp + 12);

        uint32_t bwa[4] = {bw0, bw1, bw2, bw3};
#pragma unroll
        for (int f = 0; f < 4; f++) {
            uint32_t wl = bwa[f] >> ko;
            float Epf = Epv[f], Gpf = Gpv[f];
            float p0 = (wl & 1u)   ? fmaxf(Epf * f0.x, Gpf * f0.y) : 0.f;
            float p1 = (wl & 2u)   ? fmaxf(Epf * f0.z, Gpf * f0.w) : 0.f;
            float p2 = (wl & 4u)   ? fmaxf(Epf * f1.x, Gpf * f1.y) : 0.f;
            float p3 = (wl & 8u)   ? fmaxf(Epf * f1.z, Gpf * f1.w) : 0.f;
            float p4 = (wl & 16u)  ? fmaxf(Epf * f2.x, Gpf * f2.y) : 0.f;
            float p5 = (wl & 32u)  ? fmaxf(Epf * f2.z, Gpf * f2.w) : 0.f;
            float p6 = (wl & 64u)  ? fmaxf(Epf * f3.x, Gpf * f3.y) : 0.f;
            float p7 = (wl & 128u) ? fmaxf(Epf * f3.z, Gpf * f3.w) : 0.f;
            uint4 au = {pk_bf16(p0, p1), pk_bf16(p2, p3), pk_bf16(p4, p5), pk_bf16(p6, p7)};
            short8 af = __builtin_bit_cast(short8, au);
            acc[f][0] = __builtin_amdgcn_mfma_f32_16x16x32_bf16(af, B0, acc[f][0], 0, 0, 0);
            acc[f][1] = __builtin_amdgcn_mfma_f32_16x16x32_bf16(af, B1, acc[f][1], 0, 0, 0);
            acc[f][2] = __builtin_amdgcn_mfma_f32_16x16x32_bf16(af, B2, acc[f][2], 0, 0, 0);
            acc[f][3] = __builtin_amdgcn_mfma_f32_16x16x32_bf16(af, B3, acc[f][3], 0, 0, 0);
        }
    }

    float* outp = pout + (size_t)ks * NN * DD;
    // C layout: col = l&15, row = (l>>4)*4 + r
#pragma unroll
    for (int f = 0; f < 4; f++) {
        const int orow = i0 + 16 * f + (l >> 4) * 4;
#pragma unroll
        for (int q = 0; q < 4; q++) {
            const int ocol = cg * 64 + q * 16 + rl16;
#pragma unroll
            for (int r = 0; r < 4; r++)
                outp[(size_t)(orow + r) * DD + ocol] = acc[f][q][r];
        }
    }
}

// -------- out = relu(sum of 8 partials) --------
__global__ __launch_bounds__(256) void combine8(const float* __restrict__ p,
                                                float* __restrict__ out) {
    const size_t S = (size_t)NN * DD / 4;   // float4 stride between partials
    size_t idx = (size_t)blockIdx.x * 256 + threadIdx.x;
    float4 a0 = ((const float4*)p)[idx];
    float4 a1 = ((const float4*)p)[idx + S];
    float4 a2 = ((const float4*)p)[idx + 2 * S];
    float4 a3 = ((const float4*)p)[idx + 3 * S];
    float4 a4 = ((const float4*)p)[idx + 4 * S];
    float4 a5 = ((const float4*)p)[idx + 5 * S];
    float4 a6 = ((const float4*)p)[idx + 6 * S];
    float4 a7 = ((const float4*)p)[idx + 7 * S];
    float4 o;
    o.x = fmaxf(((a0.x + a1.x) + (a2.x + a3.x)) + ((a4.x + a5.x) + (a6.x + a7.x)), 0.f);
    o.y = fmaxf(((a0.y + a1.y) + (a2.y + a3.y)) + ((a4.y + a5.y) + (a6.y + a7.y)), 0.f);
    o.z = fmaxf(((a0.z + a1.z) + (a2.z + a3.z)) + ((a4.z + a5.z) + (a6.z + a7.z)), 0.f);
    o.w = fmaxf(((a0.w + a1.w) + (a2.w + a3.w)) + ((a4.w + a5.w) + (a6.w + a7.w)), 0.f);
    ((float4*)out)[idx] = o;
}

extern "C" void kernel_launch(void* const* d_in, const int* in_sizes, int n_in,
                              void* d_out, int out_size, void* d_ws, size_t ws_size,
                              hipStream_t stream) {
    const float* x   = (const float*)d_in[0];
    const int* adj   = (const int*)d_in[1];
    const float* W1  = (const float*)d_in[2];
    const float* a1s = (const float*)d_in[3];
    const float* a1d = (const float*)d_in[4];
    const float* W2  = (const float*)d_in[5];
    const float* a2s = (const float*)d_in[6];
    const float* a2d = (const float*)d_in[7];
    float* out = (float*)d_out;

    char* ws = (char*)d_ws;
    const size_t MB = 1024ull * 1024ull;
    uint64_t*       bits  = (uint64_t*)(ws + 8 * MB);        // 8 MB
    uint32_t*       bits32= (uint32_t*)bits;
    uint32_t*       bitsT = (uint32_t*)(ws + 16 * MB);       // 8 MB
    float*          sArr  = (float*)(ws + 24 * MB);          // summed s
    float*          ddA   = sArr + NN;                       // summed dd
    float*          EpA   = sArr + 2 * NN;
    float*          GpA   = sArr + 3 * NN;
    float*          FHA   = sArr + 4 * NN;                   // 2*NN floats
    float*          s4    = sArr + 6 * NN;                   // 4*NN partials
    float*          dd4   = sArr + 10 * NN;                  // 4*NN partials
    unsigned short* Bpack = (unsigned short*)(ws + 25 * MB); // 4 MB
    float*          pout  = (float*)(ws + 32 * MB);          // 64 MB (8 partials)

    // ---------------- Layer 1 (+ shared preprocessing overlapped) ----------------
    mega1<<<dim3(3072), dim3(256), 0, stream>>>(x, W1, Bpack, a1s, a1d, s4, dd4,
                                                adj, bits);
    fhgen<<<dim3(32), dim3(256), 0, stream>>>(s4, dd4, sArr, ddA, FHA);
    mega2<<<dim3(2560), dim3(256), 0, stream>>>(bits32, bitsT, sArr, ddA, FHA, EpA, GpA);
    pv_mfma<<<dim3(1024), dim3(256), 0, stream>>>(Bpack, bitsT, FHA, EpA, GpA, pout);
    combine8<<<dim3(2048), dim3(256), 0, stream>>>(pout, out);

    // ---------------- Layer 2 ----------------
    k_gemm<<<dim3(1024), dim3(256), 0, stream>>>(out, W2, Bpack, a2s, a2d, s4, dd4);
    fhgen<<<dim3(32), dim3(256), 0, stream>>>(s4, dd4, sArr, ddA, FHA);
    k_rowstats<<<dim3(2048), dim3(256), 0, stream>>>(bits32, sArr, ddA, FHA, EpA, GpA);
    pv_mfma<<<dim3(1024), dim3(256), 0, stream>>>(Bpack, bitsT, FHA, EpA, GpA, pout);
    combine8<<<dim3(2048), dim3(256), 0, stream>>>(pout, out);
}